// Round 9
// baseline (681.409 us; speedup 1.0000x reference)
//
#include <hip/hip_runtime.h>

// Fused 4-layer RNN (LSTM,LSTM,GRU,GRU, H=64) + FC head. B=2048, T=512.
// Wave-specialized LAYER PIPELINE, TWO independent blocks per CU:
// 512 blocks x 512 threads (8 waves). Waves {0,1}=LSTM0@t=T, {2,3}=LSTM1@
// t=T-1, {4,5}=GRU0@t=T-2, {6,7}=GRU1@t=T-3; each wave owns a 32-dim
// h-chunk (2 col-tiles). 4 batch rows/block at A-rows {0,4,8,12} -> each
// lane owns 1 row x 2 dims. States double-buffered bf16 in LDS; one
// barrier per tick. Two co-resident blocks (guaranteed: 16 waves/CU =
// 4/SIMD, 4x512 regs fits the file; LDS ~29KB x2 < 160KB) have
// INDEPENDENT barriers -> phases dephase, LDS/VALU/MFMA pipes overlap.
// x fully preloaded to LDS (no in-loop staging barrier).
// exp2-native activations: weights/biases pre-scaled by -log2e / -2log2e.

#define TT 512
#define SR 72            // state row stride (shorts)
#define LOG2E 1.44269504f

typedef __attribute__((ext_vector_type(8))) short bfrag;  // 8 bf16
typedef __attribute__((ext_vector_type(4))) float facc;   // 4 f32

#define MFMA(a,b,c) __builtin_amdgcn_mfma_f32_16x16x32_bf16((a),(b),(c),0,0,0)

__device__ __forceinline__ short f2bf(float f){
  union { float f; unsigned u; } v; v.f = f;
  return (short)((v.u + 0x7fffu + ((v.u >> 16) & 1u)) >> 16);  // RNE
}
// u already scaled by -log2e: sigma(x) = 1/(1+2^u)
__device__ __forceinline__ float sigmP(float u){
  return __builtin_amdgcn_rcpf(1.0f + __builtin_amdgcn_exp2f(u));
}
// u already scaled by -2*log2e: tanh(x) = 2/(1+2^u) - 1
__device__ __forceinline__ float tanhP(float u){
  return 2.0f * __builtin_amdgcn_rcpf(1.0f + __builtin_amdgcn_exp2f(u)) - 1.0f;
}

__global__ __launch_bounds__(512) void rnn_fused(
    const float* __restrict__ x,
    const float* __restrict__ lw_ih0, const float* __restrict__ lw_hh0,
    const float* __restrict__ lb_ih0, const float* __restrict__ lb_hh0,
    const float* __restrict__ lw_ih1, const float* __restrict__ lw_hh1,
    const float* __restrict__ lb_ih1, const float* __restrict__ lb_hh1,
    const float* __restrict__ gw_ih0, const float* __restrict__ gw_hh0,
    const float* __restrict__ gb_ih0, const float* __restrict__ gb_hh0,
    const float* __restrict__ gw_ih1, const float* __restrict__ gw_hh1,
    const float* __restrict__ gb_ih1, const float* __restrict__ gb_hh1,
    const float* __restrict__ fc_w, const float* __restrict__ fc_b,
    float* __restrict__ out)
{
  __shared__ __align__(16) short S0[2][16 * SR];  // h0 (LSTM0 out)
  __shared__ __align__(16) short S1[2][16 * SR];  // h1 (LSTM1 out)
  __shared__ __align__(16) short S2[2][16 * SR];  // h2 (GRU0 out)
  __shared__ __align__(16) short S3[2][16 * SR];  // h3 (GRU1 out)
  __shared__ float xs[4][TT];                     // full x for our 4 rows
  __shared__ float hfin[4][68];

  const int tid = threadIdx.x;
  const int w     = tid >> 6;      // wave 0..7
  const int layer = w >> 1;        // 0..3
  const int lo2   = w & 1;         // h-half [lo2*32, lo2*32+32)
  const int l   = tid & 63;
  const int lq  = l >> 4;          // owns batch row lq (A-row 4*lq)
  const int lc  = l & 15;
  const int kb  = lq * 8;
  const int rb0 = blockIdx.x * 4;
  const int wrb = (4 * lq) * SR + lo2 * 32 + lc;   // + ct*16

  const float SS  = -LOG2E;          // sigmoid-gate scale
  const float ST2 = -2.0f * LOG2E;   // tanh-gate scale

  // preload all 512 timesteps of x for our 4 rows (2048 floats, 4/thread)
  {
    const int idx = tid * 4;
    const int row = idx >> 9, t = idx & 511;
    *(float4*)&xs[row][t] = *(const float4*)(x + (rb0 + row) * TT + t);
  }
  for (int i = tid; i < 16 * SR; i += 512) {
    S0[0][i] = 0; S0[1][i] = 0; S1[0][i] = 0; S1[1][i] = 0;
    S2[0][i] = 0; S2[1][i] = 0; S3[0][i] = 0; S3[1][i] = 0;
  }
  __syncthreads();

  if (layer == 0) {
    // ============ LSTM0: t = T, K=64 (h-part; x is scalar FMA) ============
    bfrag wf[4][2][2];             // [gate][col-tile][ktile]
    float wxs[4][2], bs[4][2];
    #pragma unroll
    for (int G = 0; G < 4; ++G) {
      const float sc = (G == 2) ? ST2 : SS;
      #pragma unroll
      for (int ct = 0; ct < 2; ++ct) {
        const int col = G * 64 + lo2 * 32 + ct * 16 + lc;
        #pragma unroll
        for (int kt = 0; kt < 2; ++kt) {
          bfrag f;
          #pragma unroll
          for (int j = 0; j < 8; ++j)
            f[j] = f2bf(sc * lw_hh0[col * 64 + kt * 32 + kb + j]);
          wf[G][ct][kt] = f;
        }
        wxs[G][ct] = sc * lw_ih0[col];
        bs[G][ct]  = sc * (lb_ih0[col] + lb_hh0[col]);
      }
    }
    float c0[2] = {0.f, 0.f};
    #pragma unroll 2
    for (int T = 0; T < TT + 3; ++T) {
      const int cur = T & 1, prv = cur ^ 1;
      if (T < TT) {
        const short* s = S0[prv];
        const bfrag a0 = *(const bfrag*)(s + lc * SR + kb);
        const bfrag a1 = *(const bfrag*)(s + lc * SR + 32 + kb);
        facc acc[4][2];
        #pragma unroll
        for (int G = 0; G < 4; ++G)
          #pragma unroll
          for (int ct = 0; ct < 2; ++ct) {
            facc z = {0,0,0,0};
            z = MFMA(a0, wf[G][ct][0], z);
            z = MFMA(a1, wf[G][ct][1], z);
            acc[G][ct] = z;
          }
        const float xv = xs[lq][T];
        #pragma unroll
        for (int ct = 0; ct < 2; ++ct) {
          const float i_ = sigmP(acc[0][ct][0] + xv * wxs[0][ct] + bs[0][ct]);
          const float f_ = sigmP(acc[1][ct][0] + xv * wxs[1][ct] + bs[1][ct]);
          const float g_ = tanhP(acc[2][ct][0] + xv * wxs[2][ct] + bs[2][ct]);
          const float o_ = sigmP(acc[3][ct][0] + xv * wxs[3][ct] + bs[3][ct]);
          c0[ct] = f_ * c0[ct] + i_ * g_;
          S0[cur][wrb + ct * 16] = f2bf(o_ * tanhP(c0[ct] * ST2));
        }
      }
      __syncthreads();
    }
  } else if (layer == 1) {
    // ============ LSTM1: t = T-1, K=128 ([h0_t | h1_{t-1}]) ============
    bfrag wxf[4][2][2], whf[4][2][2];
    float bs[4][2];
    #pragma unroll
    for (int G = 0; G < 4; ++G) {
      const float sc = (G == 2) ? ST2 : SS;
      #pragma unroll
      for (int ct = 0; ct < 2; ++ct) {
        const int col = G * 64 + lo2 * 32 + ct * 16 + lc;
        #pragma unroll
        for (int kt = 0; kt < 2; ++kt) {
          bfrag f0, f1;
          #pragma unroll
          for (int j = 0; j < 8; ++j) {
            const int o = col * 64 + kt * 32 + kb + j;
            f0[j] = f2bf(sc * lw_ih1[o]);
            f1[j] = f2bf(sc * lw_hh1[o]);
          }
          wxf[G][ct][kt] = f0; whf[G][ct][kt] = f1;
        }
        bs[G][ct] = sc * (lb_ih1[col] + lb_hh1[col]);
      }
    }
    float c1[2] = {0.f, 0.f};
    #pragma unroll 2
    for (int T = 0; T < TT + 3; ++T) {
      const int cur = T & 1, prv = cur ^ 1;
      if (T >= 1 && T <= TT) {
        const short* sx = S0[prv];
        const short* sh = S1[prv];
        const bfrag ax0 = *(const bfrag*)(sx + lc * SR + kb);
        const bfrag ax1 = *(const bfrag*)(sx + lc * SR + 32 + kb);
        const bfrag ah0 = *(const bfrag*)(sh + lc * SR + kb);
        const bfrag ah1 = *(const bfrag*)(sh + lc * SR + 32 + kb);
        facc acc[4][2];
        #pragma unroll
        for (int G = 0; G < 4; ++G)
          #pragma unroll
          for (int ct = 0; ct < 2; ++ct) {
            facc z = {0,0,0,0};            // one acc, 4-deep chain (x + h)
            z = MFMA(ax0, wxf[G][ct][0], z);
            z = MFMA(ax1, wxf[G][ct][1], z);
            z = MFMA(ah0, whf[G][ct][0], z);
            z = MFMA(ah1, whf[G][ct][1], z);
            acc[G][ct] = z;
          }
        #pragma unroll
        for (int ct = 0; ct < 2; ++ct) {
          const float i_ = sigmP(acc[0][ct][0] + bs[0][ct]);
          const float f_ = sigmP(acc[1][ct][0] + bs[1][ct]);
          const float g_ = tanhP(acc[2][ct][0] + bs[2][ct]);
          const float o_ = sigmP(acc[3][ct][0] + bs[3][ct]);
          c1[ct] = f_ * c1[ct] + i_ * g_;
          S1[cur][wrb + ct * 16] = f2bf(o_ * tanhP(c1[ct] * ST2));
        }
      }
      __syncthreads();
    }
  } else if (layer == 2) {
    // ============ GRU0: t = T-2 (x-part = h1_t, h-part = h2_{t-1}) ========
    bfrag gxf[3][2][2], ghf[3][2][2];
    float brz[2][2], bnx[2], bnh[2];
    #pragma unroll
    for (int G = 0; G < 3; ++G) {
      const float sc = (G == 2) ? ST2 : SS;
      #pragma unroll
      for (int ct = 0; ct < 2; ++ct) {
        const int col = G * 64 + lo2 * 32 + ct * 16 + lc;
        #pragma unroll
        for (int kt = 0; kt < 2; ++kt) {
          bfrag f0, f1;
          #pragma unroll
          for (int j = 0; j < 8; ++j) {
            const int o = col * 64 + kt * 32 + kb + j;
            f0[j] = f2bf(sc * gw_ih0[o]);
            f1[j] = f2bf(sc * gw_hh0[o]);
          }
          gxf[G][ct][kt] = f0; ghf[G][ct][kt] = f1;
        }
        if (G < 2) brz[G][ct] = sc * (gb_ih0[col] + gb_hh0[col]);
        else { bnx[ct] = sc * gb_ih0[col]; bnh[ct] = sc * gb_hh0[col]; }
      }
    }
    float h2[2] = {0.f, 0.f};
    #pragma unroll 2
    for (int T = 0; T < TT + 3; ++T) {
      const int cur = T & 1, prv = cur ^ 1;
      if (T >= 2 && T <= TT + 1) {
        const short* sx = S1[prv];
        const short* sh = S2[prv];
        const bfrag ax0 = *(const bfrag*)(sx + lc * SR + kb);
        const bfrag ax1 = *(const bfrag*)(sx + lc * SR + 32 + kb);
        const bfrag ah0 = *(const bfrag*)(sh + lc * SR + kb);
        const bfrag ah1 = *(const bfrag*)(sh + lc * SR + 32 + kb);
        facc rz[2][2], axn[2], ahn[2];
        #pragma unroll
        for (int ct = 0; ct < 2; ++ct) {
          #pragma unroll
          for (int G = 0; G < 2; ++G) {    // r,z: x+h merged chain
            facc z = {0,0,0,0};
            z = MFMA(ax0, gxf[G][ct][0], z);
            z = MFMA(ax1, gxf[G][ct][1], z);
            z = MFMA(ah0, ghf[G][ct][0], z);
            z = MFMA(ah1, ghf[G][ct][1], z);
            rz[G][ct] = z;
          }
          facc a_ = {0,0,0,0}, b_ = {0,0,0,0};  // n: x/h split (r couples)
          a_ = MFMA(ax0, gxf[2][ct][0], a_);
          a_ = MFMA(ax1, gxf[2][ct][1], a_);
          b_ = MFMA(ah0, ghf[2][ct][0], b_);
          b_ = MFMA(ah1, ghf[2][ct][1], b_);
          axn[ct] = a_; ahn[ct] = b_;
        }
        #pragma unroll
        for (int ct = 0; ct < 2; ++ct) {
          const float r_ = sigmP(rz[0][ct][0] + brz[0][ct]);
          const float z_ = sigmP(rz[1][ct][0] + brz[1][ct]);
          const float n_ = tanhP((axn[ct][0] + bnx[ct]) + r_ * (ahn[ct][0] + bnh[ct]));
          h2[ct] = n_ + z_ * (h2[ct] - n_);
          S2[cur][wrb + ct * 16] = f2bf(h2[ct]);
        }
      }
      __syncthreads();
    }
  } else {
    // ============ GRU1: t = T-3 (x-part = h2_t, h-part = h3_{t-1}) ========
    bfrag gxf[3][2][2], ghf[3][2][2];
    float brz[2][2], bnx[2], bnh[2];
    #pragma unroll
    for (int G = 0; G < 3; ++G) {
      const float sc = (G == 2) ? ST2 : SS;
      #pragma unroll
      for (int ct = 0; ct < 2; ++ct) {
        const int col = G * 64 + lo2 * 32 + ct * 16 + lc;
        #pragma unroll
        for (int kt = 0; kt < 2; ++kt) {
          bfrag f0, f1;
          #pragma unroll
          for (int j = 0; j < 8; ++j) {
            const int o = col * 64 + kt * 32 + kb + j;
            f0[j] = f2bf(sc * gw_ih1[o]);
            f1[j] = f2bf(sc * gw_hh1[o]);
          }
          gxf[G][ct][kt] = f0; ghf[G][ct][kt] = f1;
        }
        if (G < 2) brz[G][ct] = sc * (gb_ih1[col] + gb_hh1[col]);
        else { bnx[ct] = sc * gb_ih1[col]; bnh[ct] = sc * gb_hh1[col]; }
      }
    }
    float h3[2] = {0.f, 0.f};
    #pragma unroll 2
    for (int T = 0; T < TT + 3; ++T) {
      const int cur = T & 1, prv = cur ^ 1;
      if (T >= 3) {
        const short* sx = S2[prv];
        const short* sh = S3[prv];
        const bfrag ax0 = *(const bfrag*)(sx + lc * SR + kb);
        const bfrag ax1 = *(const bfrag*)(sx + lc * SR + 32 + kb);
        const bfrag ah0 = *(const bfrag*)(sh + lc * SR + kb);
        const bfrag ah1 = *(const bfrag*)(sh + lc * SR + 32 + kb);
        facc rz[2][2], axn[2], ahn[2];
        #pragma unroll
        for (int ct = 0; ct < 2; ++ct) {
          #pragma unroll
          for (int G = 0; G < 2; ++G) {
            facc z = {0,0,0,0};
            z = MFMA(ax0, gxf[G][ct][0], z);
            z = MFMA(ax1, gxf[G][ct][1], z);
            z = MFMA(ah0, ghf[G][ct][0], z);
            z = MFMA(ah1, ghf[G][ct][1], z);
            rz[G][ct] = z;
          }
          facc a_ = {0,0,0,0}, b_ = {0,0,0,0};
          a_ = MFMA(ax0, gxf[2][ct][0], a_);
          a_ = MFMA(ax1, gxf[2][ct][1], a_);
          b_ = MFMA(ah0, ghf[2][ct][0], b_);
          b_ = MFMA(ah1, ghf[2][ct][1], b_);
          axn[ct] = a_; ahn[ct] = b_;
        }
        #pragma unroll
        for (int ct = 0; ct < 2; ++ct) {
          const float r_ = sigmP(rz[0][ct][0] + brz[0][ct]);
          const float z_ = sigmP(rz[1][ct][0] + brz[1][ct]);
          const float n_ = tanhP((axn[ct][0] + bnx[ct]) + r_ * (ahn[ct][0] + bnh[ct]));
          h3[ct] = n_ + z_ * (h3[ct] - n_);
          S3[cur][wrb + ct * 16] = f2bf(h3[ct]);
        }
      }
      __syncthreads();
    }
    // final hidden state -> hfin (batch row = lq)
    hfin[lq][lo2 * 32 + lc]      = h3[0];
    hfin[lq][lo2 * 32 + 16 + lc] = h3[1];
  }

  __syncthreads();
  if (tid < 4) {
    float s = fc_b[0];
    #pragma unroll 8
    for (int d = 0; d < 64; ++d) s += hfin[tid][d] * fc_w[d];
    out[rb0 + tid] = s;
  }
}

extern "C" void kernel_launch(void* const* d_in, const int* in_sizes, int n_in,
                              void* d_out, int out_size, void* d_ws, size_t ws_size,
                              hipStream_t stream) {
  const float* x      = (const float*)d_in[0];
  const float* lw_ih0 = (const float*)d_in[1];
  const float* lw_hh0 = (const float*)d_in[2];
  const float* lb_ih0 = (const float*)d_in[3];
  const float* lb_hh0 = (const float*)d_in[4];
  const float* lw_ih1 = (const float*)d_in[5];
  const float* lw_hh1 = (const float*)d_in[6];
  const float* lb_ih1 = (const float*)d_in[7];
  const float* lb_hh1 = (const float*)d_in[8];
  const float* gw_ih0 = (const float*)d_in[9];
  const float* gw_hh0 = (const float*)d_in[10];
  const float* gb_ih0 = (const float*)d_in[11];
  const float* gb_hh0 = (const float*)d_in[12];
  const float* gw_ih1 = (const float*)d_in[13];
  const float* gw_hh1 = (const float*)d_in[14];
  const float* gb_ih1 = (const float*)d_in[15];
  const float* gb_hh1 = (const float*)d_in[16];
  const float* fc_w   = (const float*)d_in[17];
  const float* fc_b   = (const float*)d_in[18];

  rnn_fused<<<dim3(2048 / 4), dim3(512), 0, stream>>>(
      x, lw_ih0, lw_hh0, lb_ih0, lb_hh0, lw_ih1, lw_hh1, lb_ih1, lb_hh1,
      gw_ih0, gw_hh0, gb_ih0, gb_hh0, gw_ih1, gw_hh1, gb_ih1, gb_hh1,
      fc_w, fc_b, (float*)d_out);
}

// Round 10
// 396.114 us; speedup vs baseline: 1.7202x; 1.7202x over previous
//
#include <hip/hip_runtime.h>

// Fused 4-layer RNN (LSTM,LSTM,GRU,GRU, H=64) + FC head. B=2048, T=512.
// ELASTIC layer pipeline with LDS flag sync (no per-tick __syncthreads):
// 256 blocks x 1024 threads (16 waves). Layer L owns waves [4L,4L+4);
// each wave owns a 16-dim h-chunk. 8 batch rows/block at A-rows
// {0,1,4,5,8,9,12,13} -> each lane owns rows m={0,1}. Each stream
// (h0,h1,h2,h3) is a 4-deep LDS ring buffer; monotonic counters cnt[4]
// (+1 per wave per tick) gate consumers/back-pressure. Drift<=1 invariant:
// cnt >= 4*(T+1) <=> all 4 group waves completed tick T.
// Bias folded into MFMA C operand (no accvgpr zero-init, no bias adds).
// exp2-native activations: weights pre-scaled by -log2e / -2log2e.

#define TT 512
#define SR 72            // state row stride (shorts)
#define SLOT (16 * SR)   // one ring slot (shorts)
#define LOG2E 1.44269504f

typedef __attribute__((ext_vector_type(8))) short bfrag;  // 8 bf16
typedef __attribute__((ext_vector_type(4))) float facc;   // 4 f32

#define MFMA(a,b,c) __builtin_amdgcn_mfma_f32_16x16x32_bf16((a),(b),(c),0,0,0)

__device__ __forceinline__ short f2bf(float f){
  union { float f; unsigned u; } v; v.f = f;
  return (short)((v.u + 0x7fffu + ((v.u >> 16) & 1u)) >> 16);  // RNE
}
// u already scaled by -log2e: sigma(x) = 1/(1+2^u)
__device__ __forceinline__ float sigmP(float u){
  return __builtin_amdgcn_rcpf(1.0f + __builtin_amdgcn_exp2f(u));
}
// u already scaled by -2*log2e: tanh(x) = 2/(1+2^u) - 1
__device__ __forceinline__ float tanhP(float u){
  return 2.0f * __builtin_amdgcn_rcpf(1.0f + __builtin_amdgcn_exp2f(u)) - 1.0f;
}
__device__ __forceinline__ void spin_ge(volatile int* p, int tgt){
  if (*p >= tgt) return;
  do { __builtin_amdgcn_s_sleep(1); } while (*p < tgt);
}
__device__ __forceinline__ facc bcast4(float v){
  facc b; b[0] = v; b[1] = v; b[2] = v; b[3] = v; return b;
}

__global__ __launch_bounds__(1024) void rnn_fused(
    const float* __restrict__ x,
    const float* __restrict__ lw_ih0, const float* __restrict__ lw_hh0,
    const float* __restrict__ lb_ih0, const float* __restrict__ lb_hh0,
    const float* __restrict__ lw_ih1, const float* __restrict__ lw_hh1,
    const float* __restrict__ lb_ih1, const float* __restrict__ lb_hh1,
    const float* __restrict__ gw_ih0, const float* __restrict__ gw_hh0,
    const float* __restrict__ gb_ih0, const float* __restrict__ gb_hh0,
    const float* __restrict__ gw_ih1, const float* __restrict__ gw_hh1,
    const float* __restrict__ gb_ih1, const float* __restrict__ gb_hh1,
    const float* __restrict__ fc_w, const float* __restrict__ fc_b,
    float* __restrict__ out)
{
  __shared__ __align__(16) short S0[4 * SLOT];  // h0 ring
  __shared__ __align__(16) short S1[4 * SLOT];  // h1 ring
  __shared__ __align__(16) short S2[4 * SLOT];  // h2 ring
  __shared__ __align__(16) short S3[4 * SLOT];  // h3 ring
  __shared__ float xs[8][TT];                   // full x for our 8 rows
  __shared__ float hfin[8][68];
  __shared__ int cnt[4];

  const int tid = threadIdx.x;
  const int w     = tid >> 6;      // wave 0..15
  const int layer = w >> 2;        // 0..3
  const int lo4   = w & 3;         // h-chunk [lo4*16, lo4*16+16)
  const int l   = tid & 63;
  const int lq  = l >> 4;          // lane owns batch rows 2lq, 2lq+1
  const int lc  = l & 15;
  const int kb  = lq * 8;
  const int rb0 = blockIdx.x * 8;
  const int wrbase = (4 * lq) * SR + lo4 * 16 + lc;   // + m*SR
  volatile int* vc = cnt;

  const float SS  = -LOG2E;          // sigmoid-gate scale
  const float ST2 = -2.0f * LOG2E;   // tanh-gate scale

  // preload all 512 timesteps of x for our 8 rows (4096 floats, 4/thread)
  {
    const int idx = tid * 4;
    const int row = idx >> 9, t0 = idx & 511;
    *(float4*)&xs[row][t0] = *(const float4*)(x + (rb0 + row) * TT + t0);
  }
  for (int i = tid; i < 4 * SLOT; i += 1024) {
    S0[i] = 0; S1[i] = 0; S2[i] = 0; S3[i] = 0;
  }
  if (tid < 4) cnt[tid] = 0;
  __syncthreads();

  if (layer == 0) {
    // ============ LSTM0: K=64 (h-part; x is scalar FMA) ============
    bfrag wf[4][2];
    float wxs[4];
    facc b4[4];
    #pragma unroll
    for (int G = 0; G < 4; ++G) {
      const float sc = (G == 2) ? ST2 : SS;
      const int col = G * 64 + lo4 * 16 + lc;
      #pragma unroll
      for (int kt = 0; kt < 2; ++kt) {
        bfrag f;
        #pragma unroll
        for (int j = 0; j < 8; ++j)
          f[j] = f2bf(sc * lw_hh0[col * 64 + kt * 32 + kb + j]);
        wf[G][kt] = f;
      }
      wxs[G] = sc * lw_ih0[col];
      b4[G]  = bcast4(sc * (lb_ih0[col] + lb_hh0[col]));
    }
    float c0[2] = {0.f, 0.f};
    #pragma unroll 2
    for (int t = 0; t < TT; ++t) {
      if (t >= 4) spin_ge(vc + 1, 4 * (t - 3));   // LSTM1 freed slot t&3
      if (t >= 1) spin_ge(vc + 0, 4 * t);         // own group done t-1
      __threadfence_block();
      const short* s = S0 + ((t - 1) & 3) * SLOT;
      const bfrag a0 = *(const bfrag*)(s + lc * SR + kb);
      const bfrag a1 = *(const bfrag*)(s + lc * SR + 32 + kb);
      facc acc[4];
      #pragma unroll
      for (int G = 0; G < 4; ++G) {
        facc z = MFMA(a0, wf[G][0], b4[G]);
        z = MFMA(a1, wf[G][1], z);
        acc[G] = z;
      }
      short* d = S0 + (t & 3) * SLOT;
      #pragma unroll
      for (int m = 0; m < 2; ++m) {
        const float xv = xs[2 * lq + m][t];
        const float i_ = sigmP(acc[0][m] + xv * wxs[0]);
        const float f_ = sigmP(acc[1][m] + xv * wxs[1]);
        const float g_ = tanhP(acc[2][m] + xv * wxs[2]);
        const float o_ = sigmP(acc[3][m] + xv * wxs[3]);
        c0[m] = f_ * c0[m] + i_ * g_;
        d[wrbase + m * SR] = f2bf(o_ * tanhP(c0[m] * ST2));
      }
      __threadfence_block();
      if (l == 0) atomicAdd(&cnt[0], 1);
    }
  } else if (layer == 1) {
    // ============ LSTM1: K=128 ([h0_t | h1_{t-1}]) ============
    bfrag wxf[4][2], whf[4][2];
    facc b4[4];
    #pragma unroll
    for (int G = 0; G < 4; ++G) {
      const float sc = (G == 2) ? ST2 : SS;
      const int col = G * 64 + lo4 * 16 + lc;
      #pragma unroll
      for (int kt = 0; kt < 2; ++kt) {
        bfrag f0, f1;
        #pragma unroll
        for (int j = 0; j < 8; ++j) {
          const int o = col * 64 + kt * 32 + kb + j;
          f0[j] = f2bf(sc * lw_ih1[o]);
          f1[j] = f2bf(sc * lw_hh1[o]);
        }
        wxf[G][kt] = f0; whf[G][kt] = f1;
      }
      b4[G] = bcast4(sc * (lb_ih1[col] + lb_hh1[col]));
    }
    float c1[2] = {0.f, 0.f};
    #pragma unroll 2
    for (int t = 0; t < TT; ++t) {
      if (t >= 4) spin_ge(vc + 2, 4 * (t - 3));   // GRU0 freed slot
      spin_ge(vc + 0, 4 * (t + 1));               // h0[t] ready
      if (t >= 1) spin_ge(vc + 1, 4 * t);         // own group done t-1
      __threadfence_block();
      const short* sx = S0 + (t & 3) * SLOT;
      const short* sh = S1 + ((t - 1) & 3) * SLOT;
      const bfrag ax0 = *(const bfrag*)(sx + lc * SR + kb);
      const bfrag ax1 = *(const bfrag*)(sx + lc * SR + 32 + kb);
      const bfrag ah0 = *(const bfrag*)(sh + lc * SR + kb);
      const bfrag ah1 = *(const bfrag*)(sh + lc * SR + 32 + kb);
      facc acc[4];
      #pragma unroll
      for (int G = 0; G < 4; ++G) {
        facc z = MFMA(ax0, wxf[G][0], b4[G]);
        z = MFMA(ax1, wxf[G][1], z);
        z = MFMA(ah0, whf[G][0], z);
        z = MFMA(ah1, whf[G][1], z);
        acc[G] = z;
      }
      short* d = S1 + (t & 3) * SLOT;
      #pragma unroll
      for (int m = 0; m < 2; ++m) {
        const float i_ = sigmP(acc[0][m]);
        const float f_ = sigmP(acc[1][m]);
        const float g_ = tanhP(acc[2][m]);
        const float o_ = sigmP(acc[3][m]);
        c1[m] = f_ * c1[m] + i_ * g_;
        d[wrbase + m * SR] = f2bf(o_ * tanhP(c1[m] * ST2));
      }
      __threadfence_block();
      if (l == 0) atomicAdd(&cnt[1], 1);
    }
  } else if (layer == 2) {
    // ============ GRU0: x-part = h1_t, h-part = h2_{t-1} ============
    bfrag gxf[3][2], ghf[3][2];
    facc brz4[2], bnx4, bnh4;
    #pragma unroll
    for (int G = 0; G < 3; ++G) {
      const float sc = (G == 2) ? ST2 : SS;
      const int col = G * 64 + lo4 * 16 + lc;
      #pragma unroll
      for (int kt = 0; kt < 2; ++kt) {
        bfrag f0, f1;
        #pragma unroll
        for (int j = 0; j < 8; ++j) {
          const int o = col * 64 + kt * 32 + kb + j;
          f0[j] = f2bf(sc * gw_ih0[o]);
          f1[j] = f2bf(sc * gw_hh0[o]);
        }
        gxf[G][kt] = f0; ghf[G][kt] = f1;
      }
      if (G < 2) brz4[G] = bcast4(sc * (gb_ih0[col] + gb_hh0[col]));
      else { bnx4 = bcast4(sc * gb_ih0[col]); bnh4 = bcast4(sc * gb_hh0[col]); }
    }
    float h2[2] = {0.f, 0.f};
    #pragma unroll 2
    for (int t = 0; t < TT; ++t) {
      if (t >= 4) spin_ge(vc + 3, 4 * (t - 3));   // GRU1 freed slot
      spin_ge(vc + 1, 4 * (t + 1));               // h1[t] ready
      if (t >= 1) spin_ge(vc + 2, 4 * t);         // own group done t-1
      __threadfence_block();
      const short* sx = S1 + (t & 3) * SLOT;
      const short* sh = S2 + ((t - 1) & 3) * SLOT;
      const bfrag ax0 = *(const bfrag*)(sx + lc * SR + kb);
      const bfrag ax1 = *(const bfrag*)(sx + lc * SR + 32 + kb);
      const bfrag ah0 = *(const bfrag*)(sh + lc * SR + kb);
      const bfrag ah1 = *(const bfrag*)(sh + lc * SR + 32 + kb);
      facc rz[2], axn, ahn;
      #pragma unroll
      for (int G = 0; G < 2; ++G) {
        facc z = MFMA(ax0, gxf[G][0], brz4[G]);
        z = MFMA(ax1, gxf[G][1], z);
        z = MFMA(ah0, ghf[G][0], z);
        z = MFMA(ah1, ghf[G][1], z);
        rz[G] = z;
      }
      axn = MFMA(ax0, gxf[2][0], bnx4);
      axn = MFMA(ax1, gxf[2][1], axn);
      ahn = MFMA(ah0, ghf[2][0], bnh4);
      ahn = MFMA(ah1, ghf[2][1], ahn);
      short* d = S2 + (t & 3) * SLOT;
      #pragma unroll
      for (int m = 0; m < 2; ++m) {
        const float r_ = sigmP(rz[0][m]);
        const float z_ = sigmP(rz[1][m]);
        const float n_ = tanhP(axn[m] + r_ * ahn[m]);
        h2[m] = n_ + z_ * (h2[m] - n_);
        d[wrbase + m * SR] = f2bf(h2[m]);
      }
      __threadfence_block();
      if (l == 0) atomicAdd(&cnt[2], 1);
    }
  } else {
    // ============ GRU1: x-part = h2_t, h-part = h3_{t-1} ============
    bfrag gxf[3][2], ghf[3][2];
    facc brz4[2], bnx4, bnh4;
    #pragma unroll
    for (int G = 0; G < 3; ++G) {
      const float sc = (G == 2) ? ST2 : SS;
      const int col = G * 64 + lo4 * 16 + lc;
      #pragma unroll
      for (int kt = 0; kt < 2; ++kt) {
        bfrag f0, f1;
        #pragma unroll
        for (int j = 0; j < 8; ++j) {
          const int o = col * 64 + kt * 32 + kb + j;
          f0[j] = f2bf(sc * gw_ih1[o]);
          f1[j] = f2bf(sc * gw_hh1[o]);
        }
        gxf[G][kt] = f0; ghf[G][kt] = f1;
      }
      if (G < 2) brz4[G] = bcast4(sc * (gb_ih1[col] + gb_hh1[col]));
      else { bnx4 = bcast4(sc * gb_ih1[col]); bnh4 = bcast4(sc * gb_hh1[col]); }
    }
    float h3[2] = {0.f, 0.f};
    #pragma unroll 2
    for (int t = 0; t < TT; ++t) {
      spin_ge(vc + 2, 4 * (t + 1));               // h2[t] ready
      if (t >= 1) spin_ge(vc + 3, 4 * t);         // own group done t-1
      __threadfence_block();
      const short* sx = S2 + (t & 3) * SLOT;
      const short* sh = S3 + ((t - 1) & 3) * SLOT;
      const bfrag ax0 = *(const bfrag*)(sx + lc * SR + kb);
      const bfrag ax1 = *(const bfrag*)(sx + lc * SR + 32 + kb);
      const bfrag ah0 = *(const bfrag*)(sh + lc * SR + kb);
      const bfrag ah1 = *(const bfrag*)(sh + lc * SR + 32 + kb);
      facc rz[2], axn, ahn;
      #pragma unroll
      for (int G = 0; G < 2; ++G) {
        facc z = MFMA(ax0, gxf[G][0], brz4[G]);
        z = MFMA(ax1, gxf[G][1], z);
        z = MFMA(ah0, ghf[G][0], z);
        z = MFMA(ah1, ghf[G][1], z);
        rz[G] = z;
      }
      axn = MFMA(ax0, gxf[2][0], bnx4);
      axn = MFMA(ax1, gxf[2][1], axn);
      ahn = MFMA(ah0, ghf[2][0], bnh4);
      ahn = MFMA(ah1, ghf[2][1], ahn);
      short* d = S3 + (t & 3) * SLOT;
      #pragma unroll
      for (int m = 0; m < 2; ++m) {
        const float r_ = sigmP(rz[0][m]);
        const float z_ = sigmP(rz[1][m]);
        const float n_ = tanhP(axn[m] + r_ * ahn[m]);
        h3[m] = n_ + z_ * (h3[m] - n_);
        d[wrbase + m * SR] = f2bf(h3[m]);
      }
      __threadfence_block();
      if (l == 0) atomicAdd(&cnt[3], 1);
    }
    // final hidden state -> hfin (batch rows 2lq, 2lq+1)
    #pragma unroll
    for (int m = 0; m < 2; ++m)
      hfin[2 * lq + m][lo4 * 16 + lc] = h3[m];
  }

  __syncthreads();
  if (tid < 8) {
    float s = fc_b[0];
    #pragma unroll 8
    for (int d = 0; d < 64; ++d) s += hfin[tid][d] * fc_w[d];
    out[rb0 + tid] = s;
  }
}

extern "C" void kernel_launch(void* const* d_in, const int* in_sizes, int n_in,
                              void* d_out, int out_size, void* d_ws, size_t ws_size,
                              hipStream_t stream) {
  const float* x      = (const float*)d_in[0];
  const float* lw_ih0 = (const float*)d_in[1];
  const float* lw_hh0 = (const float*)d_in[2];
  const float* lb_ih0 = (const float*)d_in[3];
  const float* lb_hh0 = (const float*)d_in[4];
  const float* lw_ih1 = (const float*)d_in[5];
  const float* lw_hh1 = (const float*)d_in[6];
  const float* lb_ih1 = (const float*)d_in[7];
  const float* lb_hh1 = (const float*)d_in[8];
  const float* gw_ih0 = (const float*)d_in[9];
  const float* gw_hh0 = (const float*)d_in[10];
  const float* gb_ih0 = (const float*)d_in[11];
  const float* gb_hh0 = (const float*)d_in[12];
  const float* gw_ih1 = (const float*)d_in[13];
  const float* gw_hh1 = (const float*)d_in[14];
  const float* gb_ih1 = (const float*)d_in[15];
  const float* gb_hh1 = (const float*)d_in[16];
  const float* fc_w   = (const float*)d_in[17];
  const float* fc_b   = (const float*)d_in[18];

  rnn_fused<<<dim3(2048 / 8), dim3(1024), 0, stream>>>(
      x, lw_ih0, lw_hh0, lb_ih0, lb_hh0, lw_ih1, lw_hh1, lb_ih1, lb_hh1,
      gw_ih0, gw_hh0, gb_ih0, gb_hh0, gw_ih1, gw_hh1, gb_ih1, gb_hh1,
      fc_w, fc_b, (float*)d_out);
}